// Round 12
// baseline (156.659 us; speedup 1.0000x reference)
//
#include <hip/hip_runtime.h>
#include <hip/hip_fp16.h>
#include <cmath>

#define DIM_M 1024   // B (batch)
#define DIM_K 8192   // D
#define DIM_N 4096   // U
#define SPLIT 4
#define KSPL  (DIM_K / SPLIT)   // 2048
#define BKT   32
#define NTT   (KSPL / BKT)      // 64 K-tiles per block
#define NB    1024              // scatter bins
#define EPB   8192              // entries per block in hist/reorder

typedef __attribute__((ext_vector_type(8))) _Float16 half8;
typedef __attribute__((ext_vector_type(4))) float floatx4;

struct __align__(8) Half4 { __half2 a, b; };

__device__ inline void gload_lds16(const void* g, void* l) {
    __builtin_amdgcn_global_load_lds(
        (const __attribute__((address_space(1))) void*)g,
        (__attribute__((address_space(3))) void*)l, 16, 0, 0);
}

__global__ void cvt_f2h(const floatx4* __restrict__ in, Half4* __restrict__ out, int n4) {
    int i = blockIdx.x * blockDim.x + threadIdx.x;
    if (i < n4) {
        floatx4 f = in[i];
        Half4 h;
        h.a = __floats2half2_rn(f.x, f.y);
        h.b = __floats2half2_rn(f.z, f.w);
        out[i] = h;
    }
}

// ---- scatter pipeline: bin -> scan -> reorder(LDS-clustered) -> accumulate --

__global__ __launch_bounds__(512) void hist_k(const int* __restrict__ ind,
                                              unsigned* __restrict__ cnt, int nnz) {
    __shared__ unsigned h[NB];
    const int tid = threadIdx.x;
    for (int i = tid; i < NB; i += 512) h[i] = 0u;
    __syncthreads();
    const int base = blockIdx.x * EPB;
    const int lim = min(nnz - base, EPB);
    const int4* ip = (const int4*)(ind + 2 * (size_t)base);
    for (int k2 = tid; k2 < lim / 2; k2 += 512) {
        int4 w = ip[k2];
        atomicAdd(&h[w.y >> 2], 1u);
        atomicAdd(&h[w.w >> 2], 1u);
    }
    if ((lim & 1) && tid == 0) {
        int u = ind[2 * (size_t)(base + lim - 1) + 1];
        atomicAdd(&h[u >> 2], 1u);
    }
    __syncthreads();
    for (int i = tid; i < NB; i += 512) cnt[(size_t)blockIdx.x * NB + i] = h[i];
}

__global__ void scanb_k(unsigned* cnt, unsigned* __restrict__ bb, int nblk) {
    __shared__ unsigned s[256];
    const int tid = threadIdx.x, bin = blockIdx.x;
    unsigned carry = 0;
    for (int c0 = 0; c0 < nblk; c0 += 256) {
        int b = c0 + tid;
        unsigned v = (b < nblk) ? cnt[(size_t)b * NB + bin] : 0u;
        s[tid] = v;
        __syncthreads();
        for (int off = 1; off < 256; off <<= 1) {
            unsigned add = (tid >= off) ? s[tid - off] : 0u;
            __syncthreads();
            s[tid] += add;
            __syncthreads();
        }
        if (b < nblk) cnt[(size_t)b * NB + bin] = carry + s[tid] - v;
        carry += s[255];
        __syncthreads();
    }
    if (tid == 0) bb[bin] = carry;
}

__global__ void scant_k(unsigned* bb) {
    __shared__ unsigned s[NB];
    const int tid = threadIdx.x;
    unsigned v = bb[tid];
    s[tid] = v;
    __syncthreads();
    for (int off = 1; off < NB; off <<= 1) {
        unsigned add = (tid >= off) ? s[tid - off] : 0u;
        __syncthreads();
        s[tid] += add;
        __syncthreads();
    }
    bb[tid] = s[tid] - v;
    if (tid == NB - 1) bb[NB] = s[tid];
}

__global__ __launch_bounds__(512) void reorder_k(const int* __restrict__ ind,
                                                 const float* __restrict__ kv,
                                                 const unsigned* __restrict__ start,
                                                 const unsigned* __restrict__ bb,
                                                 uint2* __restrict__ ebuf, int nnz) {
    extern __shared__ char rsm[];
    uint2*    buf  = (uint2*)rsm;                 // 64 KB
    unsigned* gofs = (unsigned*)(rsm + 65536);    // 32 KB
    unsigned* cur  = (unsigned*)(rsm + 98304);    //  4 KB
    unsigned* dl   = (unsigned*)(rsm + 102400);   //  4 KB
    unsigned* ss   = (unsigned*)(rsm + 106496);   //  2 KB
    const int tid = threadIdx.x, blk = blockIdx.x;
    const int base = blk * EPB;
    const int lim = min(nnz - base, EPB);
    const int4*   ip = (const int4*)(ind + 2 * (size_t)base);
    const float2* vp = (const float2*)(kv + base);

    for (int i = tid; i < NB; i += 512) cur[i] = 0u;
    __syncthreads();
    for (int k2 = tid; k2 < lim / 2; k2 += 512) {
        int4 w = ip[k2];
        atomicAdd(&cur[w.y >> 2], 1u);
        atomicAdd(&cur[w.w >> 2], 1u);
    }
    if ((lim & 1) && tid == 0) {
        int u = ind[2 * (size_t)(base + lim - 1) + 1];
        atomicAdd(&cur[u >> 2], 1u);
    }
    __syncthreads();
    unsigned c0 = cur[2 * tid], c1 = cur[2 * tid + 1];
    unsigned own = c0 + c1;
    ss[tid] = own;
    __syncthreads();
    for (int off = 1; off < 512; off <<= 1) {
        unsigned t = (tid >= off) ? ss[tid - off] : 0u;
        __syncthreads();
        ss[tid] += t;
        __syncthreads();
    }
    unsigned e0 = ss[tid] - own;
    unsigned e1 = e0 + c0;
    __syncthreads();
    cur[2 * tid]     = e0;
    cur[2 * tid + 1] = e1;
    unsigned g0 = bb[2 * tid]     + start[(size_t)blk * NB + 2 * tid];
    unsigned g1 = bb[2 * tid + 1] + start[(size_t)blk * NB + 2 * tid + 1];
    dl[2 * tid]     = g0 - e0;
    dl[2 * tid + 1] = g1 - e1;
    __syncthreads();
    for (int k2 = tid; k2 < lim / 2; k2 += 512) {
        int4 w = ip[k2];
        float2 v = vp[k2];
        int b0 = w.y >> 2, b1 = w.w >> 2;
        unsigned r0 = atomicAdd(&cur[b0], 1u);
        buf[r0]  = make_uint2(((unsigned)(w.y & 3) << 13) | (unsigned)w.x, __float_as_uint(v.x));
        gofs[r0] = dl[b0] + r0;
        unsigned r1 = atomicAdd(&cur[b1], 1u);
        buf[r1]  = make_uint2(((unsigned)(w.w & 3) << 13) | (unsigned)w.z, __float_as_uint(v.y));
        gofs[r1] = dl[b1] + r1;
    }
    if ((lim & 1) && tid == 0) {
        size_t e = (size_t)base + lim - 1;
        int d = ind[2 * e], u = ind[2 * e + 1];
        int b = u >> 2;
        unsigned r = atomicAdd(&cur[b], 1u);
        buf[r]  = make_uint2(((unsigned)(u & 3) << 13) | (unsigned)d, __float_as_uint(kv[e]));
        gofs[r] = dl[b] + r;
    }
    __syncthreads();
    for (int j = tid; j < lim; j += 512)
        ebuf[gofs[j]] = buf[j];
}

__global__ __launch_bounds__(512) void accum_k(const uint2* __restrict__ ebuf,
                                               const unsigned* __restrict__ bb,
                                               Half4* __restrict__ wh4) {
    extern __shared__ float reg[];            // 128 KB
    floatx4* reg4 = (floatx4*)reg;
    const int tid = threadIdx.x, bin = blockIdx.x;
    for (int i = tid; i < 8192; i += 512) reg4[i] = floatx4{0.f, 0.f, 0.f, 0.f};
    __syncthreads();
    const unsigned s0 = bb[bin], s1 = bb[bin + 1];
    for (unsigned e = s0 + tid; e < s1; e += 512) {
        uint2 p = ebuf[e];
        atomicAdd(&reg[p.x], __uint_as_float(p.y));
    }
    __syncthreads();
    for (int i = tid; i < 8192; i += 512) {
        floatx4 f = reg4[i];
        Half4 h;
        h.a = __floats2half2_rn(f.x, f.y);
        h.b = __floats2half2_rn(f.z, f.w);
        wh4[(size_t)bin * 8192 + i] = h;
    }
}

// ---------------------------------------------------------------------------
// CROSS-TILE register double-buffered GEMM (AITER K-loop shape). 256x256
// tile, BKT=32, ring-4 LDS (4 x 32KB), 8 waves of 128x64, 2 waves/SIMD.
// Per K-tile body: {12 ds_read (tile t+1 frags -> spare reg set) || 4
// global_load_lds (tile t+3) || 32 MFMA (tile t frags)} — all independent,
// NO wait between them. Trailing counted waits only: vmcnt(4) (tile t+1
// staged; t+2,t+3 in flight), lgkmcnt(0) (t+1 frags in regs), 1 barrier.
// MFMAs never wait on loads issued in the same body -> LDS port and matrix
// pipe overlap. (R2/R5/R6/R8/R9/R10 all fed same-tile MFMAs from same-tile
// reads -> forced read->wait->MFMA serialization; all landed at ~LDS+MFMA
// sum. This removes the intra-tile dependency entirely.)
// Hazards: stage(t+3) overwrites buf[t-1], reads of which were lgkm'd at
// body(t-2) and barrier-confirmed; vmcnt(4) ordering gives tile t+1 landed.
// Tail staging overruns into adjacent ws regions (never consumed).
// ---------------------------------------------------------------------------
__global__ __launch_bounds__(512, 2) void gemm8_k(
    const _Float16* __restrict__ Ah,   // [M][K] fp16
    const _Float16* __restrict__ Bh,   // [N][K] fp16
    _Float16*       __restrict__ part) // [SPLIT][M][N] fp16
{
    extern __shared__ char smem[];     // ring buf c: A[256][32] @ c*32768, B @ +16384

    const int tid  = threadIdx.x;
    const int lane = tid & 63;
    const int wave = tid >> 6;           // 0..7

    const int bid = blockIdx.x;
    const int swz = (bid & 7) * 32 + (bid >> 3);
    const int n0  = (swz >> 4) * 256;
    const int rem = swz & 15;
    const int m0  = (rem >> 2) * 256;
    const int sp  = rem & 3;
    const size_t kbase = (size_t)sp * KSPL;

    // staging: row = tid>>2, phys chunk = tid&3, src chunk ^= (row>>1)&3
    const int srow = tid >> 2;                   // 0..127
    const int sch  = (tid & 3) ^ ((tid >> 3) & 3);
    const _Float16* aSg = Ah + (size_t)(m0 + srow) * DIM_K + kbase + sch * 8;
    const _Float16* bSg = Bh + (size_t)(n0 + srow) * DIM_K + kbase + sch * 8;
    const int wofs = wave * 1024;

    // read side: wave tile 128x64 (wrm = M half, wn = N quarter)
    const int wrm = wave >> 2;
    const int wn  = wave & 3;
    const int q   = lane >> 4;
    const char* aRd = smem + (wrm * 128 + (lane & 15)) * 64;
    const char* bRd = smem + 16384 + (wn * 64 + (lane & 15)) * 64;
    const int ch = (q ^ ((lane >> 1) & 3)) * 16;

    floatx4 acc[8][4] = {};
    half8 aF0[8], bF0[4], aF1[8], bF1[4];

#define STAGE(SB)                                                             \
    { gload_lds16(aSg,                       smem + (SB) * 32768 + wofs);     \
      gload_lds16(aSg + (size_t)128 * DIM_K, smem + (SB) * 32768 + 8192 + wofs); \
      gload_lds16(bSg,                       smem + (SB) * 32768 + 16384 + wofs); \
      gload_lds16(bSg + (size_t)128 * DIM_K, smem + (SB) * 32768 + 24576 + wofs); \
      aSg += BKT; bSg += BKT; }

#define READF(RA, RB, CB)                                                     \
    { _Pragma("unroll") for (int i = 0; i < 8; ++i)                           \
        RA[i] = *(const half8*)(aRd + (CB) * 32768 + i * 1024 + ch);          \
      _Pragma("unroll") for (int i = 0; i < 4; ++i)                           \
        RB[i] = *(const half8*)(bRd + (CB) * 32768 + i * 1024 + ch); }

#define MM(RA, RB)                                                            \
    { __builtin_amdgcn_s_setprio(1);                                         \
      _Pragma("unroll") for (int mi = 0; mi < 8; ++mi)                        \
        _Pragma("unroll") for (int ni = 0; ni < 4; ++ni)                      \
          acc[mi][ni] = __builtin_amdgcn_mfma_f32_16x16x32_f16(               \
              RA[mi], RB[ni], acc[mi][ni], 0, 0, 0);                          \
      __builtin_amdgcn_s_setprio(0); }

// body(t): read frags of t+1 (buf CBN), stage t+3 (buf SB), MFMA on tile t
// (AU/BU, loaded last body). Waits trail everything; nothing inside blocks.
#define BODY(CBN, SB, AU, BU, AL, BL)                                         \
    READF(AL, BL, CBN)                                                        \
    STAGE(SB)                                                                 \
    MM(AU, BU)                                                                \
    asm volatile("s_waitcnt vmcnt(4) lgkmcnt(0)" ::: "memory");               \
    __builtin_amdgcn_sched_barrier(0);                                        \
    __builtin_amdgcn_s_barrier();                                             \
    __builtin_amdgcn_sched_barrier(0);

    // prologue: stage tiles 0,1,2; tiles 0,1 landed when <=4 outstanding
    STAGE(0) STAGE(1) STAGE(2)
    asm volatile("s_waitcnt vmcnt(4)" ::: "memory");
    __builtin_amdgcn_s_barrier();
    READF(aF0, bF0, 0)                 // tile 0 frags
    asm volatile("s_waitcnt lgkmcnt(0)" ::: "memory");
    __builtin_amdgcn_sched_barrier(0);

    for (int it = 0; it < NTT / 4; ++it) {
        BODY(1, 3, aF0, bF0, aF1, bF1)   // t%4=0: frags t+1<-buf1, stage->buf3
        BODY(2, 0, aF1, bF1, aF0, bF0)   // t%4=1
        BODY(3, 1, aF0, bF0, aF1, bF1)   // t%4=2
        BODY(0, 2, aF1, bF1, aF0, bF0)   // t%4=3
    }

#undef BODY
#undef MM
#undef READF
#undef STAGE

    // epilogue: fp16 partials (C/D layout: col = lane&15, row = q*4 + r)
    _Float16* pbase = part + (size_t)sp * DIM_M * DIM_N;
    #pragma unroll
    for (int ni = 0; ni < 4; ++ni) {
        const int col = n0 + wn * 64 + ni * 16 + (lane & 15);
        #pragma unroll
        for (int mi = 0; mi < 8; ++mi) {
            const int row = m0 + wrm * 128 + mi * 16 + (q << 2);
            #pragma unroll
            for (int r = 0; r < 4; ++r)
                pbase[(size_t)(row + r) * DIM_N + col] = (_Float16)acc[mi][ni][r];
        }
    }
}

// out = tanh(sum_splits(fp16 part) + bias), 4 outputs/thread
__global__ void reduce_tanh(const Half4* __restrict__ part, const float* __restrict__ bias,
                            floatx4* __restrict__ out) {
    const int n4 = DIM_M * DIM_N / 4;
    int i = blockIdx.x * blockDim.x + threadIdx.x;
    if (i < n4) {
        float sx = 0.f, sy = 0.f, sz = 0.f, sw = 0.f;
        #pragma unroll
        for (int sp = 0; sp < SPLIT; ++sp) {
            Half4 p = part[(size_t)sp * n4 + i];
            float2 lo = __half22float2(p.a);
            float2 hi = __half22float2(p.b);
            sx += lo.x; sy += lo.y; sz += hi.x; sw += hi.y;
        }
        floatx4 b = ((const floatx4*)bias)[i & (DIM_N / 4 - 1)];
        floatx4 o;
        o.x = tanhf(sx + b.x);
        o.y = tanhf(sy + b.y);
        o.z = tanhf(sz + b.z);
        o.w = tanhf(sw + b.w);
        out[i] = o;
    }
}

extern "C" void kernel_launch(void* const* d_in, const int* in_sizes, int n_in,
                              void* d_out, int out_size, void* d_ws, size_t ws_size,
                              hipStream_t stream) {
    const float* x    = (const float*)d_in[0];
    const float* kv   = (const float*)d_in[1];
    const float* bias = (const float*)d_in[2];
    const int*   ind  = (const int*)d_in[3];
    float* out = (float*)d_out;
    const int nnz = in_sizes[1];

    char* ws = (char*)d_ws;
    _Float16* wh = (_Float16*)ws;                               // [N][K] fp16, 64 MB
    const size_t whBytes = (size_t)DIM_N * DIM_K * 2;
    _Float16* xh = (_Float16*)(ws + whBytes);                   // [M][K] fp16, 16 MB
    const size_t xhBytes = (size_t)DIM_M * DIM_K * 2;
    _Float16* part = (_Float16*)(ws + whBytes + xhBytes);       // [SPLIT][M][N] fp16, 32 MB
    const size_t partBytes = (size_t)SPLIT * DIM_M * DIM_N * 2;
    uint2* ebuf = (uint2*)(ws + whBytes + xhBytes + partBytes); // nnz*8 B (<=16 MB)
    const size_t ebufBytes = (size_t)16 << 20;
    unsigned* cnt = (unsigned*)(ws + whBytes + xhBytes + partBytes + ebufBytes); // 4 MB
    const size_t cntBytes = (size_t)1024 * NB * 4;
    unsigned* bb = (unsigned*)(ws + whBytes + xhBytes + partBytes + ebufBytes + cntBytes); // NB+1

    const int xN4 = (int)((size_t)DIM_M * DIM_K / 4);
    const int oN4 = DIM_M * DIM_N / 4;
    const int nblk = (nnz + EPB - 1) / EPB;

    cvt_f2h<<<(xN4 + 255) / 256, 256, 0, stream>>>((const floatx4*)x, (Half4*)xh, xN4);
    hist_k<<<nblk, 512, 0, stream>>>(ind, cnt, nnz);
    scanb_k<<<NB, 256, 0, stream>>>(cnt, bb, nblk);
    scant_k<<<1, NB, 0, stream>>>(bb);

    hipFuncSetAttribute((const void*)reorder_k,
                        hipFuncAttributeMaxDynamicSharedMemorySize, 131072);
    reorder_k<<<nblk, 512, 110592, stream>>>(ind, kv, cnt, bb, ebuf, nnz);

    hipFuncSetAttribute((const void*)accum_k,
                        hipFuncAttributeMaxDynamicSharedMemorySize, 131072);
    accum_k<<<NB, 512, 131072, stream>>>(ebuf, bb, (Half4*)wh);

    hipFuncSetAttribute((const void*)gemm8_k,
                        hipFuncAttributeMaxDynamicSharedMemorySize, 131072);
    gemm8_k<<<dim3(256), 512, 131072, stream>>>(xh, wh, part);

    reduce_tanh<<<(oN4 + 255) / 256, 256, 0, stream>>>((const Half4*)part, bias, (floatx4*)out);
}

// Round 13
// 125.243 us; speedup vs baseline: 1.2508x; 1.2508x over previous
//
#include <hip/hip_runtime.h>
#include <hip/hip_fp16.h>
#include <cmath>

#define DIM_M 1024   // B (batch)
#define DIM_K 8192   // D
#define DIM_N 4096   // U
#define SPLIT 4
#define KSPL  (DIM_K / SPLIT)   // 2048
#define BKT   64
#define NT    (KSPL / BKT)      // 32 K-tiles per block
#define NB    1024              // scatter bins (4 u-rows = 128 KB fp32 region each)
#define EPB   8192              // entries per block in cluster

typedef __attribute__((ext_vector_type(8))) _Float16 half8;
typedef __attribute__((ext_vector_type(4))) float floatx4;

struct __align__(8) Half4 { __half2 a, b; };

__device__ inline void gload_lds16(const void* g, void* l) {
    __builtin_amdgcn_global_load_lds(
        (const __attribute__((address_space(1))) void*)g,
        (__attribute__((address_space(3))) void*)l, 16, 0, 0);
}

__global__ void cvt_f2h(const floatx4* __restrict__ in, Half4* __restrict__ out, int n4) {
    int i = blockIdx.x * blockDim.x + threadIdx.x;
    if (i < n4) {
        floatx4 f = in[i];
        Half4 h;
        h.a = __floats2half2_rn(f.x, f.y);
        h.b = __floats2half2_rn(f.z, f.w);
        out[i] = h;
    }
}

// ---------------------------------------------------------------------------
// ONE-PASS cluster: local hist + local exclusive scan + LDS scatter-by-bin +
// block-local contiguous writeout + per-block bin offsets. Replaces the old
// hist/scanb/scant/reorder chain (global sort is unnecessary: accumulation is
// order-free, so accum can walk per-block segments directly).
// ---------------------------------------------------------------------------
__global__ __launch_bounds__(512) void cluster_k(const int* __restrict__ ind,
                                                 const float* __restrict__ kv,
                                                 uint2* __restrict__ ebuf,
                                                 unsigned* __restrict__ ofs,  // [nblk][NB+1]
                                                 int nnz) {
    extern __shared__ char csm[];
    uint2*    buf = (uint2*)csm;                  // 64 KB: entries clustered by bin
    unsigned* cur = (unsigned*)(csm + 65536);     //  4 KB: hist -> cursor
    unsigned* ss  = (unsigned*)(csm + 69632);     //  2 KB: 512 pair-sums for scan
    const int tid = threadIdx.x, blk = blockIdx.x;
    const int base = blk * EPB;
    const int lim = min(nnz - base, EPB);
    const int4*   ip = (const int4*)(ind + 2 * (size_t)base);
    const float2* vp = (const float2*)(kv + base);

    // 1) local hist (bin = u>>2)
    for (int i = tid; i < NB; i += 512) cur[i] = 0u;
    __syncthreads();
    for (int k2 = tid; k2 < lim / 2; k2 += 512) {
        int4 w = ip[k2];
        atomicAdd(&cur[w.y >> 2], 1u);
        atomicAdd(&cur[w.w >> 2], 1u);
    }
    if ((lim & 1) && tid == 0) {
        int u = ind[2 * (size_t)(base + lim - 1) + 1];
        atomicAdd(&cur[u >> 2], 1u);
    }
    __syncthreads();
    // 2) exclusive scan over 1024 bins (2 bins/thread)
    unsigned c0 = cur[2 * tid], c1 = cur[2 * tid + 1];
    unsigned own = c0 + c1;
    ss[tid] = own;
    __syncthreads();
    for (int off = 1; off < 512; off <<= 1) {
        unsigned t = (tid >= off) ? ss[tid - off] : 0u;
        __syncthreads();
        ss[tid] += t;
        __syncthreads();
    }
    unsigned e0 = ss[tid] - own;
    unsigned e1 = e0 + c0;
    __syncthreads();
    cur[2 * tid]     = e0;
    cur[2 * tid + 1] = e1;
    unsigned* obase = ofs + (size_t)blk * (NB + 1);
    obase[2 * tid]     = e0;
    obase[2 * tid + 1] = e1;
    if (tid == 511) obase[NB] = ss[511];   // = lim
    __syncthreads();
    // 3) scatter into LDS by bin
    for (int k2 = tid; k2 < lim / 2; k2 += 512) {
        int4 w = ip[k2];
        float2 v = vp[k2];
        unsigned r0 = atomicAdd(&cur[w.y >> 2], 1u);
        buf[r0] = make_uint2(((unsigned)(w.y & 3) << 13) | (unsigned)w.x, __float_as_uint(v.x));
        unsigned r1 = atomicAdd(&cur[w.w >> 2], 1u);
        buf[r1] = make_uint2(((unsigned)(w.w & 3) << 13) | (unsigned)w.z, __float_as_uint(v.y));
    }
    if ((lim & 1) && tid == 0) {
        size_t e = (size_t)base + lim - 1;
        int d = ind[2 * e], u = ind[2 * e + 1];
        unsigned r = atomicAdd(&cur[u >> 2], 1u);
        buf[r] = make_uint2(((unsigned)(u & 3) << 13) | (unsigned)d, __float_as_uint(kv[e]));
    }
    __syncthreads();
    // 4) block-local contiguous writeout (fully coalesced)
    for (int j = tid; j < lim; j += 512)
        ebuf[(size_t)blk * EPB + j] = buf[j];
}

// ---------------------------------------------------------------------------
// Per-bin accumulate: walk this bin's segment in each cluster block (one
// thread per block-segment, ~8 entries each, L2-resident), ds_add into a
// 128 KB fp32 LDS region, then dense fp16 writeout (replaces zero-fill too).
// ---------------------------------------------------------------------------
__global__ __launch_bounds__(512) void accum_k(const uint2* __restrict__ ebuf,
                                               const unsigned* __restrict__ ofs,
                                               int nblk,
                                               Half4* __restrict__ wh4) {
    extern __shared__ float reg[];            // 32768 floats = 128 KB
    floatx4* reg4 = (floatx4*)reg;
    const int tid = threadIdx.x, bin = blockIdx.x;
    for (int i = tid; i < 8192; i += 512) reg4[i] = floatx4{0.f, 0.f, 0.f, 0.f};
    __syncthreads();
    for (int sb = tid; sb < nblk; sb += 512) {
        const unsigned* ob = ofs + (size_t)sb * (NB + 1) + bin;
        unsigned o0 = ob[0], o1 = ob[1];
        const uint2* p = ebuf + (size_t)sb * EPB;
        for (unsigned e = o0; e < o1; ++e) {
            uint2 v = p[e];
            atomicAdd(&reg[v.x], __uint_as_float(v.y));   // ds_add_f32
        }
    }
    __syncthreads();
    for (int i = tid; i < 8192; i += 512) {
        floatx4 f = reg4[i];
        Half4 h;
        h.a = __floats2half2_rn(f.x, f.y);
        h.b = __floats2half2_rn(f.z, f.w);
        wh4[(size_t)bin * 8192 + i] = h;
    }
}

// ---------------------------------------------------------------------------
// GEMM: measured-best config (R7): 256x256 split-K tile, BKT=64, 1024 thr
// (16 waves of 64x64 -> acc[4][4]=64 VGPR -> 4 waves/SIMD), ring-2 LDS
// 2x64KB, per K-tile 2 phases {8 ds_read -> lgkm(0) -> 16 MFMA}, 1 barrier-
// pair + batched STAGE + counted vmcnt(4). Raw s_barrier only. fp16 partials.
// (R5/R6/R8/R9/R10/R11 schedule variants all <= this; plateau is structural.)
// ---------------------------------------------------------------------------
__global__ __launch_bounds__(1024, 4) void gemm8_k(
    const _Float16* __restrict__ Ah,   // [M][K] fp16
    const _Float16* __restrict__ Bh,   // [N][K] fp16
    _Float16*       __restrict__ part) // [SPLIT][M][N] fp16
{
    extern __shared__ char smem[];

    const int tid  = threadIdx.x;
    const int lane = tid & 63;
    const int wave = tid >> 6;           // 0..15

    const int bid = blockIdx.x;
    const int swz = (bid & 7) * 32 + (bid >> 3);
    const int n0  = (swz >> 4) * 256;
    const int rem = swz & 15;
    const int m0  = (rem >> 2) * 256;
    const int sp  = rem & 3;
    const size_t kbase = (size_t)sp * KSPL;

    const int srow = tid >> 3;                   // 0..127
    const int sch  = (tid & 7) ^ (srow & 7);
    const _Float16* aSg = Ah + (size_t)(m0 + srow) * DIM_K + kbase + sch * 8;
    const _Float16* bSg = Bh + (size_t)(n0 + srow) * DIM_K + kbase + sch * 8;
    char* aLg = smem + wave * 1024;              // + C*65536 + p*16384
    char* bLg = smem + 32768 + wave * 1024;

    const int wn  = wave & 3;            // N quadrant
    const int wrm = wave >> 2;           // M quadrant
    const int q   = lane >> 4;
    const int l7  = lane & 7;
    const char* aRd = smem + (wrm * 64 + (lane & 15)) * 128;
    const char* bRd = smem + 32768 + (wn * 64 + (lane & 15)) * 128;
    const int ch0 = ((0 * 4 + q) ^ l7) * 16;
    const int ch1 = ((1 * 4 + q) ^ l7) * 16;

    floatx4 acc[4][4] = {};
    half8 aF[4], bF[4];

#define STAGE(C)                                                              \
    { _Pragma("unroll") for (int p = 0; p < 2; ++p) {                         \
        gload_lds16(aSg + (size_t)p * (128 * DIM_K), aLg + (C) * 65536 + p * 16384); \
        gload_lds16(bSg + (size_t)p * (128 * DIM_K), bLg + (C) * 65536 + p * 16384); } \
      aSg += BKT; bSg += BKT; }

#define PH(C, CH)                                                             \
    { _Pragma("unroll") for (int i = 0; i < 4; ++i)                           \
        aF[i] = *(const half8*)(aRd + (C) * 65536 + i * 2048 + (CH));         \
      _Pragma("unroll") for (int i = 0; i < 4; ++i)                           \
        bF[i] = *(const half8*)(bRd + (C) * 65536 + i * 2048 + (CH));         \
      asm volatile("s_waitcnt lgkmcnt(0)" ::: "memory");                      \
      __builtin_amdgcn_sched_barrier(0);                                      \
      __builtin_amdgcn_s_setprio(1);                                          \
      _Pragma("unroll") for (int mi = 0; mi < 4; ++mi)                        \
        _Pragma("unroll") for (int ni = 0; ni < 4; ++ni)                      \
          acc[mi][ni] = __builtin_amdgcn_mfma_f32_16x16x32_f16(               \
              aF[mi], bF[ni], acc[mi][ni], 0, 0, 0);                          \
      __builtin_amdgcn_s_setprio(0); }

#define KTILE(C) PH(C, ch0) PH(C, ch1)

    STAGE(0)
    STAGE(1)
    asm volatile("s_waitcnt vmcnt(4)" ::: "memory");
    __builtin_amdgcn_s_barrier();

    for (int t2 = 0; t2 < NT / 2; ++t2) {
        KTILE(0)
        __builtin_amdgcn_s_barrier();
        if (t2 < NT / 2 - 1) {
            STAGE(0)
            asm volatile("s_waitcnt vmcnt(4)" ::: "memory");
        } else {
            asm volatile("s_waitcnt vmcnt(0)" ::: "memory");
        }
        __builtin_amdgcn_s_barrier();
        KTILE(1)
        if (t2 < NT / 2 - 1) {
            __builtin_amdgcn_s_barrier();
            STAGE(1)
            asm volatile("s_waitcnt vmcnt(4)" ::: "memory");
            __builtin_amdgcn_s_barrier();
        }
    }

#undef KTILE
#undef PH
#undef STAGE

    // epilogue: fp16 partials (C/D layout: col = lane&15, row = q*4 + r)
    _Float16* pbase = part + (size_t)sp * DIM_M * DIM_N;
    #pragma unroll
    for (int ni = 0; ni < 4; ++ni) {
        const int col = n0 + wn * 64 + ni * 16 + (lane & 15);
        #pragma unroll
        for (int mi = 0; mi < 4; ++mi) {
            const int row = m0 + wrm * 64 + mi * 16 + (q << 2);
            #pragma unroll
            for (int r = 0; r < 4; ++r)
                pbase[(size_t)(row + r) * DIM_N + col] = (_Float16)acc[mi][ni][r];
        }
    }
}

// out = tanh(sum_splits(fp16 part) + bias), 4 outputs/thread
__global__ void reduce_tanh(const Half4* __restrict__ part, const float* __restrict__ bias,
                            floatx4* __restrict__ out) {
    const int n4 = DIM_M * DIM_N / 4;
    int i = blockIdx.x * blockDim.x + threadIdx.x;
    if (i < n4) {
        float sx = 0.f, sy = 0.f, sz = 0.f, sw = 0.f;
        #pragma unroll
        for (int sp = 0; sp < SPLIT; ++sp) {
            Half4 p = part[(size_t)sp * n4 + i];
            float2 lo = __half22float2(p.a);
            float2 hi = __half22float2(p.b);
            sx += lo.x; sy += lo.y; sz += hi.x; sw += hi.y;
        }
        floatx4 b = ((const floatx4*)bias)[i & (DIM_N / 4 - 1)];
        floatx4 o;
        o.x = tanhf(sx + b.x);
        o.y = tanhf(sy + b.y);
        o.z = tanhf(sz + b.z);
        o.w = tanhf(sw + b.w);
        out[i] = o;
    }
}

extern "C" void kernel_launch(void* const* d_in, const int* in_sizes, int n_in,
                              void* d_out, int out_size, void* d_ws, size_t ws_size,
                              hipStream_t stream) {
    const float* x    = (const float*)d_in[0];
    const float* kv   = (const float*)d_in[1];
    const float* bias = (const float*)d_in[2];
    const int*   ind  = (const int*)d_in[3];
    float* out = (float*)d_out;
    const int nnz = in_sizes[1];

    char* ws = (char*)d_ws;
    _Float16* wh = (_Float16*)ws;                               // [N][K] fp16, 64 MB
    const size_t whBytes = (size_t)DIM_N * DIM_K * 2;
    _Float16* xh = (_Float16*)(ws + whBytes);                   // [M][K] fp16, 16 MB
    const size_t xhBytes = (size_t)DIM_M * DIM_K * 2;
    _Float16* part = (_Float16*)(ws + whBytes + xhBytes);       // [SPLIT][M][N] fp16, 32 MB
    const size_t partBytes = (size_t)SPLIT * DIM_M * DIM_N * 2;
    uint2* ebuf = (uint2*)(ws + whBytes + xhBytes + partBytes); // nblk*EPB*8 B (<=16 MB)
    const size_t ebufBytes = (size_t)16 << 20;
    unsigned* ofs = (unsigned*)(ws + whBytes + xhBytes + partBytes + ebufBytes); // [nblk][NB+1], ~1 MB

    const int xN4 = (int)((size_t)DIM_M * DIM_K / 4);
    const int oN4 = DIM_M * DIM_N / 4;
    const int nblk = (nnz + EPB - 1) / EPB;

    cvt_f2h<<<(xN4 + 255) / 256, 256, 0, stream>>>((const floatx4*)x, (Half4*)xh, xN4);

    hipFuncSetAttribute((const void*)cluster_k,
                        hipFuncAttributeMaxDynamicSharedMemorySize, 71680);
    cluster_k<<<nblk, 512, 71680, stream>>>(ind, kv, ebuf, ofs, nnz);

    hipFuncSetAttribute((const void*)accum_k,
                        hipFuncAttributeMaxDynamicSharedMemorySize, 131072);
    accum_k<<<NB, 512, 131072, stream>>>(ebuf, ofs, nblk, (Half4*)wh);

    hipFuncSetAttribute((const void*)gemm8_k,
                        hipFuncAttributeMaxDynamicSharedMemorySize, 131072);
    gemm8_k<<<dim3(256), 1024, 131072, stream>>>(xh, wh, part);

    reduce_tanh<<<(oN4 + 255) / 256, 256, 0, stream>>>((const Half4*)part, bias, (floatx4*)out);
}

// Round 14
// 115.901 us; speedup vs baseline: 1.3517x; 1.0806x over previous
//
#include <hip/hip_runtime.h>
#include <hip/hip_fp16.h>
#include <cmath>

#define DIM_M 1024   // B (batch)
#define DIM_K 8192   // D
#define DIM_N 4096   // U
#define SPLIT 4
#define KSPL  (DIM_K / SPLIT)   // 2048
#define BKT   64
#define NT    (KSPL / BKT)      // 32 K-tiles per block
#define NB    1024              // scatter bins (4 u-rows = 128 KB fp32 region each)
#define EPB   8192              // entries per block in cluster
#define CVTB  1024              // cvt tail blocks fused into cluster grid

typedef __attribute__((ext_vector_type(8))) _Float16 half8;
typedef __attribute__((ext_vector_type(4))) float floatx4;

struct __align__(8) Half4 { __half2 a, b; };

__device__ inline void gload_lds16(const void* g, void* l) {
    __builtin_amdgcn_global_load_lds(
        (const __attribute__((address_space(1))) void*)g,
        (__attribute__((address_space(3))) void*)l, 16, 0, 0);
}

// ---------------------------------------------------------------------------
// Fused prep kernel. Blocks [0, nblk): one-pass cluster (local hist + scan +
// LDS scatter-by-bin + block-local contiguous writeout + per-block offsets).
// Blocks [nblk, nblk+CVTB): x fp32 -> fp16 convert (streaming BW) — fused so
// its HBM streaming overlaps the cluster blocks' LDS-atomic latency phases.
// ---------------------------------------------------------------------------
__global__ __launch_bounds__(512) void cluster_k(const int* __restrict__ ind,
                                                 const float* __restrict__ kv,
                                                 uint2* __restrict__ ebuf,
                                                 unsigned* __restrict__ ofs,  // [nblk][NB+1]
                                                 int nnz, int nblk,
                                                 const floatx4* __restrict__ xin,
                                                 Half4* __restrict__ xout) {
    extern __shared__ char csm[];
    const int tid = threadIdx.x;

    if (blockIdx.x >= nblk) {
        // ---- cvt branch: 4 float4s/thread, stride-512 coalesced ----
        const int cb = blockIdx.x - nblk;
        const int base = cb * 2048;
        #pragma unroll
        for (int j = 0; j < 4; ++j) {
            int i = base + j * 512 + tid;
            floatx4 f = xin[i];
            Half4 h;
            h.a = __floats2half2_rn(f.x, f.y);
            h.b = __floats2half2_rn(f.z, f.w);
            xout[i] = h;
        }
        return;
    }

    uint2*    buf = (uint2*)csm;                  // 64 KB: entries clustered by bin
    unsigned* cur = (unsigned*)(csm + 65536);     //  4 KB: hist -> cursor
    unsigned* ss  = (unsigned*)(csm + 69632);     //  2 KB: 512 pair-sums for scan
    const int blk = blockIdx.x;
    const int base = blk * EPB;
    const int lim = min(nnz - base, EPB);
    const int4*   ip = (const int4*)(ind + 2 * (size_t)base);
    const float2* vp = (const float2*)(kv + base);

    // 1) local hist (bin = u>>2)
    for (int i = tid; i < NB; i += 512) cur[i] = 0u;
    __syncthreads();
    for (int k2 = tid; k2 < lim / 2; k2 += 512) {
        int4 w = ip[k2];
        atomicAdd(&cur[w.y >> 2], 1u);
        atomicAdd(&cur[w.w >> 2], 1u);
    }
    if ((lim & 1) && tid == 0) {
        int u = ind[2 * (size_t)(base + lim - 1) + 1];
        atomicAdd(&cur[u >> 2], 1u);
    }
    __syncthreads();
    // 2) exclusive scan over 1024 bins (2 bins/thread)
    unsigned c0 = cur[2 * tid], c1 = cur[2 * tid + 1];
    unsigned own = c0 + c1;
    ss[tid] = own;
    __syncthreads();
    for (int off = 1; off < 512; off <<= 1) {
        unsigned t = (tid >= off) ? ss[tid - off] : 0u;
        __syncthreads();
        ss[tid] += t;
        __syncthreads();
    }
    unsigned e0 = ss[tid] - own;
    unsigned e1 = e0 + c0;
    __syncthreads();
    cur[2 * tid]     = e0;
    cur[2 * tid + 1] = e1;
    unsigned* obase = ofs + (size_t)blk * (NB + 1);
    obase[2 * tid]     = e0;
    obase[2 * tid + 1] = e1;
    if (tid == 511) obase[NB] = ss[511];   // = lim
    __syncthreads();
    // 3) scatter into LDS by bin
    for (int k2 = tid; k2 < lim / 2; k2 += 512) {
        int4 w = ip[k2];
        float2 v = vp[k2];
        unsigned r0 = atomicAdd(&cur[w.y >> 2], 1u);
        buf[r0] = make_uint2(((unsigned)(w.y & 3) << 13) | (unsigned)w.x, __float_as_uint(v.x));
        unsigned r1 = atomicAdd(&cur[w.w >> 2], 1u);
        buf[r1] = make_uint2(((unsigned)(w.w & 3) << 13) | (unsigned)w.z, __float_as_uint(v.y));
    }
    if ((lim & 1) && tid == 0) {
        size_t e = (size_t)base + lim - 1;
        int d = ind[2 * e], u = ind[2 * e + 1];
        unsigned r = atomicAdd(&cur[u >> 2], 1u);
        buf[r] = make_uint2(((unsigned)(u & 3) << 13) | (unsigned)d, __float_as_uint(kv[e]));
    }
    __syncthreads();
    // 4) block-local contiguous writeout (fully coalesced)
    for (int j = tid; j < lim; j += 512)
        ebuf[(size_t)blk * EPB + j] = buf[j];
}

// ---------------------------------------------------------------------------
// Per-bin accumulate: 2 threads per block-segment (parity-split entries —
// halves the serial dependent-load chain, 416/512 lanes active at nblk=208),
// ds_add into 128 KB fp32 LDS, dense fp16 writeout (replaces zero-fill too).
// ---------------------------------------------------------------------------
__global__ __launch_bounds__(512) void accum_k(const uint2* __restrict__ ebuf,
                                               const unsigned* __restrict__ ofs,
                                               int nblk,
                                               Half4* __restrict__ wh4) {
    extern __shared__ float reg[];            // 32768 floats = 128 KB
    floatx4* reg4 = (floatx4*)reg;
    const int tid = threadIdx.x, bin = blockIdx.x;
    for (int i = tid; i < 8192; i += 512) reg4[i] = floatx4{0.f, 0.f, 0.f, 0.f};
    __syncthreads();
    for (int s2 = tid; s2 < 2 * nblk; s2 += 512) {
        const int sb = s2 >> 1;
        const unsigned* ob = ofs + (size_t)sb * (NB + 1) + bin;
        unsigned o0 = ob[0] + (s2 & 1), o1 = ob[1];
        const uint2* p = ebuf + (size_t)sb * EPB;
        for (unsigned e = o0; e < o1; e += 2) {
            uint2 v = p[e];
            atomicAdd(&reg[v.x], __uint_as_float(v.y));   // ds_add_f32
        }
    }
    __syncthreads();
    for (int i = tid; i < 8192; i += 512) {
        floatx4 f = reg4[i];
        Half4 h;
        h.a = __floats2half2_rn(f.x, f.y);
        h.b = __floats2half2_rn(f.z, f.w);
        wh4[(size_t)bin * 8192 + i] = h;
    }
}

// ---------------------------------------------------------------------------
// GEMM: measured-best config (R7): 256x256 split-K tile, BKT=64, 1024 thr
// (16 waves of 64x64 -> acc[4][4]=64 VGPR -> 4 waves/SIMD), ring-2 LDS
// 2x64KB, per K-tile 2 phases {8 ds_read -> lgkm(0) -> 16 MFMA}, 1 barrier-
// pair + batched STAGE + counted vmcnt(4). Raw s_barrier only. fp16 partials.
// (R5/R6/R8/R9/R10/R11 schedule variants all <= this; plateau is structural.)
// ---------------------------------------------------------------------------
__global__ __launch_bounds__(1024, 4) void gemm8_k(
    const _Float16* __restrict__ Ah,   // [M][K] fp16
    const _Float16* __restrict__ Bh,   // [N][K] fp16
    _Float16*       __restrict__ part) // [SPLIT][M][N] fp16
{
    extern __shared__ char smem[];

    const int tid  = threadIdx.x;
    const int lane = tid & 63;
    const int wave = tid >> 6;           // 0..15

    const int bid = blockIdx.x;
    const int swz = (bid & 7) * 32 + (bid >> 3);
    const int n0  = (swz >> 4) * 256;
    const int rem = swz & 15;
    const int m0  = (rem >> 2) * 256;
    const int sp  = rem & 3;
    const size_t kbase = (size_t)sp * KSPL;

    const int srow = tid >> 3;                   // 0..127
    const int sch  = (tid & 7) ^ (srow & 7);
    const _Float16* aSg = Ah + (size_t)(m0 + srow) * DIM_K + kbase + sch * 8;
    const _Float16* bSg = Bh + (size_t)(n0 + srow) * DIM_K + kbase + sch * 8;
    char* aLg = smem + wave * 1024;              // + C*65536 + p*16384
    char* bLg = smem + 32768 + wave * 1024;

    const int wn  = wave & 3;            // N quadrant
    const int wrm = wave >> 2;           // M quadrant
    const int q   = lane >> 4;
    const int l7  = lane & 7;
    const char* aRd = smem + (wrm * 64 + (lane & 15)) * 128;
    const char* bRd = smem + 32768 + (wn * 64 + (lane & 15)) * 128;
    const int ch0 = ((0 * 4 + q) ^ l7) * 16;
    const int ch1 = ((1 * 4 + q) ^ l7) * 16;

    floatx4 acc[4][4] = {};
    half8 aF[4], bF[4];

#define STAGE(C)                                                              \
    { _Pragma("unroll") for (int p = 0; p < 2; ++p) {                         \
        gload_lds16(aSg + (size_t)p * (128 * DIM_K), aLg + (C) * 65536 + p * 16384); \
        gload_lds16(bSg + (size_t)p * (128 * DIM_K), bLg + (C) * 65536 + p * 16384); } \
      aSg += BKT; bSg += BKT; }

#define PH(C, CH)                                                             \
    { _Pragma("unroll") for (int i = 0; i < 4; ++i)                           \
        aF[i] = *(const half8*)(aRd + (C) * 65536 + i * 2048 + (CH));         \
      _Pragma("unroll") for (int i = 0; i < 4; ++i)                           \
        bF[i] = *(const half8*)(bRd + (C) * 65536 + i * 2048 + (CH));         \
      asm volatile("s_waitcnt lgkmcnt(0)" ::: "memory");                      \
      __builtin_amdgcn_sched_barrier(0);                                      \
      __builtin_amdgcn_s_setprio(1);                                          \
      _Pragma("unroll") for (int mi = 0; mi < 4; ++mi)                        \
        _Pragma("unroll") for (int ni = 0; ni < 4; ++ni)                      \
          acc[mi][ni] = __builtin_amdgcn_mfma_f32_16x16x32_f16(               \
              aF[mi], bF[ni], acc[mi][ni], 0, 0, 0);                          \
      __builtin_amdgcn_s_setprio(0); }

#define KTILE(C) PH(C, ch0) PH(C, ch1)

    STAGE(0)
    STAGE(1)
    asm volatile("s_waitcnt vmcnt(4)" ::: "memory");
    __builtin_amdgcn_s_barrier();

    for (int t2 = 0; t2 < NT / 2; ++t2) {
        KTILE(0)
        __builtin_amdgcn_s_barrier();
        if (t2 < NT / 2 - 1) {
            STAGE(0)
            asm volatile("s_waitcnt vmcnt(4)" ::: "memory");
        } else {
            asm volatile("s_waitcnt vmcnt(0)" ::: "memory");
        }
        __builtin_amdgcn_s_barrier();
        KTILE(1)
        if (t2 < NT / 2 - 1) {
            __builtin_amdgcn_s_barrier();
            STAGE(1)
            asm volatile("s_waitcnt vmcnt(4)" ::: "memory");
            __builtin_amdgcn_s_barrier();
        }
    }

#undef KTILE
#undef PH
#undef STAGE

    // epilogue: fp16 partials (C/D layout: col = lane&15, row = q*4 + r)
    _Float16* pbase = part + (size_t)sp * DIM_M * DIM_N;
    #pragma unroll
    for (int ni = 0; ni < 4; ++ni) {
        const int col = n0 + wn * 64 + ni * 16 + (lane & 15);
        #pragma unroll
        for (int mi = 0; mi < 4; ++mi) {
            const int row = m0 + wrm * 64 + mi * 16 + (q << 2);
            #pragma unroll
            for (int r = 0; r < 4; ++r)
                pbase[(size_t)(row + r) * DIM_N + col] = (_Float16)acc[mi][ni][r];
        }
    }
}

// out = tanh(sum_splits(fp16 part) + bias), 4 outputs/thread
__global__ void reduce_tanh(const Half4* __restrict__ part, const float* __restrict__ bias,
                            floatx4* __restrict__ out) {
    const int n4 = DIM_M * DIM_N / 4;
    int i = blockIdx.x * blockDim.x + threadIdx.x;
    if (i < n4) {
        float sx = 0.f, sy = 0.f, sz = 0.f, sw = 0.f;
        #pragma unroll
        for (int sp = 0; sp < SPLIT; ++sp) {
            Half4 p = part[(size_t)sp * n4 + i];
            float2 lo = __half22float2(p.a);
            float2 hi = __half22float2(p.b);
            sx += lo.x; sy += lo.y; sz += hi.x; sw += hi.y;
        }
        floatx4 b = ((const floatx4*)bias)[i & (DIM_N / 4 - 1)];
        floatx4 o;
        o.x = tanhf(sx + b.x);
        o.y = tanhf(sy + b.y);
        o.z = tanhf(sz + b.z);
        o.w = tanhf(sw + b.w);
        out[i] = o;
    }
}

extern "C" void kernel_launch(void* const* d_in, const int* in_sizes, int n_in,
                              void* d_out, int out_size, void* d_ws, size_t ws_size,
                              hipStream_t stream) {
    const float* x    = (const float*)d_in[0];
    const float* kv   = (const float*)d_in[1];
    const float* bias = (const float*)d_in[2];
    const int*   ind  = (const int*)d_in[3];
    float* out = (float*)d_out;
    const int nnz = in_sizes[1];

    char* ws = (char*)d_ws;
    _Float16* wh = (_Float16*)ws;                               // [N][K] fp16, 64 MB
    const size_t whBytes = (size_t)DIM_N * DIM_K * 2;
    _Float16* xh = (_Float16*)(ws + whBytes);                   // [M][K] fp16, 16 MB
    const size_t xhBytes = (size_t)DIM_M * DIM_K * 2;
    _Float16* part = (_Float16*)(ws + whBytes + xhBytes);       // [SPLIT][M][N] fp16, 32 MB
    const size_t partBytes = (size_t)SPLIT * DIM_M * DIM_N * 2;
    uint2* ebuf = (uint2*)(ws + whBytes + xhBytes + partBytes); // nblk*EPB*8 B (<=16 MB)
    const size_t ebufBytes = (size_t)16 << 20;
    unsigned* ofs = (unsigned*)(ws + whBytes + xhBytes + partBytes + ebufBytes); // [nblk][NB+1], ~1 MB

    const int oN4 = DIM_M * DIM_N / 4;
    const int nblk = (nnz + EPB - 1) / EPB;

    hipFuncSetAttribute((const void*)cluster_k,
                        hipFuncAttributeMaxDynamicSharedMemorySize, 71680);
    cluster_k<<<nblk + CVTB, 512, 71680, stream>>>(ind, kv, ebuf, ofs, nnz, nblk,
                                                   (const floatx4*)x, (Half4*)xh);

    hipFuncSetAttribute((const void*)accum_k,
                        hipFuncAttributeMaxDynamicSharedMemorySize, 131072);
    accum_k<<<NB, 512, 131072, stream>>>(ebuf, ofs, nblk, (Half4*)wh);

    hipFuncSetAttribute((const void*)gemm8_k,
                        hipFuncAttributeMaxDynamicSharedMemorySize, 131072);
    gemm8_k<<<dim3(256), 1024, 131072, stream>>>(xh, wh, part);

    reduce_tanh<<<(oN4 + 255) / 256, 256, 0, stream>>>((const Half4*)part, bias, (floatx4*)out);
}